// Round 4
// baseline (1198.549 us; speedup 1.0000x reference)
//
#include <hip/hip_runtime.h>

// Problem constants
constexpr int Bz = 512;   // batch
constexpr int Tz = 256;   // seq len
constexpr int Hz = 256;   // hidden
constexpr int Pz = 14;    // predict dim
constexpr int GB = 16;    // batch groups
constexpr int GS = 16;    // hidden slices per group
constexpr int BT = 32;    // batch per group
constexpr int HU = 16;    // hidden units per slice
constexpr int KP = 264;   // h staging row stride (bf16 elems), 16B-aligned rows
constexpr int XS = 260;   // x LDS row stride (floats), 16B-aligned rows

typedef short s8v __attribute__((ext_vector_type(8)));
typedef float f4v __attribute__((ext_vector_type(4)));
typedef unsigned long long u64;

__device__ __forceinline__ short f2bf(float f) {
  unsigned u = __float_as_uint(f);
  u = (u + 0x7fffu + ((u >> 16) & 1u)) >> 16;   // RNE
  return (short)u;
}
__device__ __forceinline__ float bf2f(short s) {
  return __uint_as_float(((unsigned)(unsigned short)s) << 16);
}
__device__ __forceinline__ float sigm(float v) { return 1.0f / (1.0f + __expf(-v)); }
__device__ __forceinline__ float tanh_f(float v) { return 1.0f - 2.0f / (__expf(2.0f * v) + 1.0f); }

// R4: weights live in REGISTERS as prebuilt MFMA A-fragments (96 VGPR), fused
// L0+L1 kt-loop reuses h0 fragments (ds_reads 72->32/thread/step), x preloaded
// to LDS, shuffle-packed epilogue stores (no gate LDS round-trip), 2 syncthreads
// + all-wave poll per step (post-poll barrier provably unnecessary: counter pass
// implies every wave everywhere is past its staging-buffer reads).
__global__ void __launch_bounds__(256, 1)
lstm2(const float* __restrict__ x,
      const float* __restrict__ w_ih0, const float* __restrict__ w_hh0,
      const float* __restrict__ b_ih0, const float* __restrict__ b_hh0,
      const float* __restrict__ w_ih1, const float* __restrict__ w_hh1,
      const float* __restrict__ b_ih1, const float* __restrict__ b_hh1,
      const float* __restrict__ w_lin, const float* __restrict__ b_lin,
      float* __restrict__ out,
      unsigned* __restrict__ bars,
      short* __restrict__ h0g, short* __restrict__ h1g)
{
  const int blk  = blockIdx.x;
  const int g    = blk >> 4;      // batch group
  const int sl   = blk & 15;      // hidden slice
  const int tid  = threadIdx.x;
  const int wave = tid >> 6;
  const int lane = tid & 63;
  const int q    = lane >> 4;
  const int l15  = lane & 15;
  const int gbase = g * BT;

  extern __shared__ char smem_raw[];
  short* h0s = (short*)smem_raw;          // [32][KP] staged h0[s-1]
  short* h1s = h0s + 32 * KP;             // [32][KP] staged h1[s-2]
  float* xls = (float*)(h1s + 32 * KP);   // [32][XS] all x for this group's batches
  float* wls = xls + 32 * XS;             // [14][256] w_lin fp32 (head, sl==0 only)

  // ---- weights -> register A-fragments. A-frag row m = l15 -> global weight
  // row rr = wave*16+l15; LDS-era ordering rr = unit*4+gate kept so that C/D
  // acc[r] = gate r of unit (wave*4+q). k of frag j = kt*32 + q*8 + j. ----
  s8v W0r[8], W1ir[8], W1hr[8];
  {
    int rr = wave * 16 + l15;
    int grow = (rr & 3) * Hz + sl * HU + (rr >> 2);
    const float* p0 = w_hh0 + (size_t)grow * Hz;
    const float* p1 = w_ih1 + (size_t)grow * Hz;
    const float* p2 = w_hh1 + (size_t)grow * Hz;
    #pragma unroll
    for (int kt = 0; kt < 8; ++kt) {
      int k0 = kt * 32 + q * 8;
      f4v a0 = *(const f4v*)(p0 + k0), a1 = *(const f4v*)(p0 + k0 + 4);
      f4v b0 = *(const f4v*)(p1 + k0), b1 = *(const f4v*)(p1 + k0 + 4);
      f4v c0v = *(const f4v*)(p2 + k0), c1v = *(const f4v*)(p2 + k0 + 4);
      s8v w0, w1, w2;
      #pragma unroll
      for (int j = 0; j < 4; ++j) {
        w0[j] = f2bf(a0[j]); w0[4 + j] = f2bf(a1[j]);
        w1[j] = f2bf(b0[j]); w1[4 + j] = f2bf(b1[j]);
        w2[j] = f2bf(c0v[j]); w2[4 + j] = f2bf(c1v[j]);
      }
      W0r[kt] = w0; W1ir[kt] = w1; W1hr[kt] = w2;
    }
  }
  // per-lane epilogue constants: unit = wave*4+q, gates r=0..3
  const int myunit = wave * 4 + q;
  float wihR[4], b0R[4], b1R[4];
  #pragma unroll
  for (int r = 0; r < 4; ++r) {
    int grow = r * Hz + sl * HU + myunit;
    wihR[r] = w_ih0[grow];
    b0R[r]  = b_ih0[grow] + b_hh0[grow];
    b1R[r]  = b_ih1[grow] + b_hh1[grow];
  }
  float c0a = 0.f, c0b = 0.f, c1a = 0.f, c1b = 0.f;

  // ---- preload x for this group's 32 batches: xls[b][t] ----
  for (int i = tid; i < BT * (Tz / 4); i += 256) {   // 2048 float4
    int b = i >> 6, c4 = i & 63;
    f4v v = *(const f4v*)(x + (size_t)(gbase + b) * Tz + c4 * 4);
    *(f4v*)(xls + b * XS + c4 * 4) = v;
  }
  if (sl == 0) {
    for (int i = tid; i < Pz * Hz / 4; i += 256)
      ((f4v*)wls)[i] = ((const f4v*)w_lin)[i];
  }

  unsigned* bar = bars + (g << 6);   // 256B-separated counter per group

  for (int s = 0; s <= Tz; ++s) {
    // ---- stage h0[s-1] (buf (s+1)&1) and h1[s-2] (buf s&1): sc1 loads -> LDS ----
    {
      const u64* h0src = (const u64*)h0g + (size_t)(((s + 1) & 1) * Bz + gbase) * 64;
      const u64* h1src = (const u64*)h1g + (size_t)(((s    ) & 1) * Bz + gbase) * 64;
      u64 r0[8], r1[8];
      #pragma unroll
      for (int k2 = 0; k2 < 8; ++k2) {
        int b = wave + k2 * 4;
        r0[k2] = __hip_atomic_load(h0src + (size_t)b * 64 + lane,
                                   __ATOMIC_RELAXED, __HIP_MEMORY_SCOPE_AGENT);
        r1[k2] = __hip_atomic_load(h1src + (size_t)b * 64 + lane,
                                   __ATOMIC_RELAXED, __HIP_MEMORY_SCOPE_AGENT);
      }
      #pragma unroll
      for (int k2 = 0; k2 < 8; ++k2) {
        int b = wave + k2 * 4;
        *(u64*)(h0s + b * KP + lane * 4) = r0[k2];
        *(u64*)(h1s + b * KP + lane * 4) = r1[k2];
      }
    }
    __syncthreads();

    // ---- fused MFMA: L0 (16) + L1 (32), weights from regs, h0 frags shared ----
    f4v aL0a = {0.f,0.f,0.f,0.f}, aL0b = {0.f,0.f,0.f,0.f};
    f4v aL1a = {0.f,0.f,0.f,0.f}, aL1b = {0.f,0.f,0.f,0.f};
    const short* H0f = h0s + l15 * KP + q * 8;
    const short* H1f = h1s + l15 * KP + q * 8;
    #pragma unroll
    for (int kt = 0; kt < 8; ++kt) {
      s8v ha = *(const s8v*)(H0f + kt * 32);
      s8v hb = *(const s8v*)(H0f + 16 * KP + kt * 32);
      s8v ga = *(const s8v*)(H1f + kt * 32);
      s8v gb = *(const s8v*)(H1f + 16 * KP + kt * 32);
      aL0a = __builtin_amdgcn_mfma_f32_16x16x32_bf16(W0r[kt],  ha, aL0a, 0, 0, 0);
      aL0b = __builtin_amdgcn_mfma_f32_16x16x32_bf16(W0r[kt],  hb, aL0b, 0, 0, 0);
      aL1a = __builtin_amdgcn_mfma_f32_16x16x32_bf16(W1ir[kt], ha, aL1a, 0, 0, 0);
      aL1b = __builtin_amdgcn_mfma_f32_16x16x32_bf16(W1ir[kt], hb, aL1b, 0, 0, 0);
      aL1a = __builtin_amdgcn_mfma_f32_16x16x32_bf16(W1hr[kt], ga, aL1a, 0, 0, 0);
      aL1b = __builtin_amdgcn_mfma_f32_16x16x32_bf16(W1hr[kt], gb, aL1b, 0, 0, 0);
    }

    // ---- in-register epilogues; results as bf16 shorts in int regs ----
    int v0a = 0, v0b = 0, v1a = 0, v1b = 0;
    if (s < Tz) {
      float xa = xls[l15 * XS + s], xb = xls[(16 + l15) * XS + s];
      float ia = sigm  (aL0a[0] + xa * wihR[0] + b0R[0]);
      float fa = sigm  (aL0a[1] + xa * wihR[1] + b0R[1]);
      float ga = tanh_f(aL0a[2] + xa * wihR[2] + b0R[2]);
      float oa = sigm  (aL0a[3] + xa * wihR[3] + b0R[3]);
      c0a = fa * c0a + ia * ga;
      v0a = (int)(unsigned short)f2bf(oa * tanh_f(c0a));
      float ib = sigm  (aL0b[0] + xb * wihR[0] + b0R[0]);
      float fb = sigm  (aL0b[1] + xb * wihR[1] + b0R[1]);
      float gb2 = tanh_f(aL0b[2] + xb * wihR[2] + b0R[2]);
      float ob = sigm  (aL0b[3] + xb * wihR[3] + b0R[3]);
      c0b = fb * c0b + ib * gb2;
      v0b = (int)(unsigned short)f2bf(ob * tanh_f(c0b));
    }
    if (s >= 1) {
      float ia = sigm  (aL1a[0] + b1R[0]);
      float fa = sigm  (aL1a[1] + b1R[1]);
      float ga = tanh_f(aL1a[2] + b1R[2]);
      float oa = sigm  (aL1a[3] + b1R[3]);
      c1a = fa * c1a + ia * ga;
      v1a = (int)(unsigned short)f2bf(oa * tanh_f(c1a));
      float ib = sigm  (aL1b[0] + b1R[0]);
      float fb = sigm  (aL1b[1] + b1R[1]);
      float gb2 = tanh_f(aL1b[2] + b1R[2]);
      float ob = sigm  (aL1b[3] + b1R[3]);
      c1b = fb * c1b + ib * gb2;
      v1b = (int)(unsigned short)f2bf(ob * tanh_f(c1b));
    }

    // ---- shuffle-pack across q (lanes +16,+32): q==0 lanes hold u64 of 4 units ----
    int t0a = v0a | (__shfl_down(v0a, 16) << 16);
    int t0b = v0b | (__shfl_down(v0b, 16) << 16);
    int t1a = v1a | (__shfl_down(v1a, 16) << 16);
    int t1b = v1b | (__shfl_down(v1b, 16) << 16);
    u64 u0a = (u64)(unsigned)t0a | ((u64)(unsigned)__shfl_down(t0a, 32) << 32);
    u64 u0b = (u64)(unsigned)t0b | ((u64)(unsigned)__shfl_down(t0b, 32) << 32);
    u64 u1a = (u64)(unsigned)t1a | ((u64)(unsigned)__shfl_down(t1a, 32) << 32);
    u64 u1b = (u64)(unsigned)t1b | ((u64)(unsigned)__shfl_down(t1b, 32) << 32);
    if (q == 0) {
      int col = sl * 4 + wave;
      if (s < Tz) {
        u64* d0 = (u64*)h0g + (size_t)((s & 1) * Bz + gbase) * 64 + col;
        __hip_atomic_store(d0 + (size_t)l15 * 64,       u0a, __ATOMIC_RELAXED, __HIP_MEMORY_SCOPE_AGENT);
        __hip_atomic_store(d0 + (size_t)(16 + l15) * 64, u0b, __ATOMIC_RELAXED, __HIP_MEMORY_SCOPE_AGENT);
      }
      if (s >= 1) {
        u64* d1 = (u64*)h1g + (size_t)(((s - 1) & 1) * Bz + gbase) * 64 + col;
        __hip_atomic_store(d1 + (size_t)l15 * 64,       u1a, __ATOMIC_RELAXED, __HIP_MEMORY_SCOPE_AGENT);
        __hip_atomic_store(d1 + (size_t)(16 + l15) * 64, u1b, __ATOMIC_RELAXED, __HIP_MEMORY_SCOPE_AGENT);
      }
    }

    // ---- barrier: syncthreads drains all waves' sc1 stores (vmcnt(0) before
    // s_barrier), tid0 bumps group counter, ALL waves poll. No trailing
    // syncthreads needed: counter==tgt implies every wave in the group is past
    // its staging-buffer reads, so next-step LDS overwrite is safe. ----
    __syncthreads();
    if (tid == 0)
      __hip_atomic_fetch_add(bar, 1u, __ATOMIC_RELAXED, __HIP_MEMORY_SCOPE_AGENT);
    const unsigned tgt = (unsigned)(GS * (s + 1));
    while (__hip_atomic_load(bar, __ATOMIC_RELAXED, __HIP_MEMORY_SCOPE_AGENT) < tgt)
      __builtin_amdgcn_s_sleep(1);
  }

  // ---- final linear head (slice-0 blocks): out = h1[T-1] @ w_lin^T + b_lin ----
  if (sl == 0) {
    const u64* hU = (const u64*)h1g + (size_t)(((Tz - 1) & 1) * Bz + gbase) * 64;
    for (int i = tid; i < BT * 64; i += 256) {
      int b = i >> 6, ch = i & 63;
      u64 v = __hip_atomic_load(hU + (size_t)b * 64 + ch,
                                __ATOMIC_RELAXED, __HIP_MEMORY_SCOPE_AGENT);
      *(u64*)(h0s + b * KP + ch * 4) = v;
    }
    __syncthreads();
    for (int i = tid; i < BT * Pz; i += 256) {
      int b = i / Pz, p = i - b * Pz;
      const float* wr = wls + p * Hz;
      float acc = b_lin[p];
      for (int ch = 0; ch < 64; ++ch) {
        u64 hv = *(const u64*)(h0s + b * KP + ch * 4);
        f4v wv = *(const f4v*)(wr + ch * 4);
        acc += bf2f((short)(hv      )) * wv[0];
        acc += bf2f((short)(hv >> 16)) * wv[1];
        acc += bf2f((short)(hv >> 32)) * wv[2];
        acc += bf2f((short)(hv >> 48)) * wv[3];
      }
      out[(gbase + b) * Pz + p] = acc;
    }
  }
}

extern "C" void kernel_launch(void* const* d_in, const int* in_sizes, int n_in,
                              void* d_out, int out_size, void* d_ws, size_t ws_size,
                              hipStream_t stream) {
  const float* x     = (const float*)d_in[0];
  const float* w_ih0 = (const float*)d_in[1];
  const float* w_hh0 = (const float*)d_in[2];
  const float* b_ih0 = (const float*)d_in[3];
  const float* b_hh0 = (const float*)d_in[4];
  const float* w_ih1 = (const float*)d_in[5];
  const float* w_hh1 = (const float*)d_in[6];
  const float* b_ih1 = (const float*)d_in[7];
  const float* b_hh1 = (const float*)d_in[8];
  const float* w_lin = (const float*)d_in[9];
  const float* b_lin = (const float*)d_in[10];
  float* out = (float*)d_out;

  unsigned char* ws = (unsigned char*)d_ws;
  unsigned* bars = (unsigned*)ws;                              // 16KB: barrier counters
  short* h0g = (short*)(ws + 16384);                           // [2][B][H] bf16
  short* h1g = (short*)(ws + 16384 + 2 * Bz * Hz * 2);         // [2][B][H] bf16
  size_t clear_bytes = 16384 + 2 * (size_t)(2 * Bz * Hz * 2);
  hipMemsetAsync(d_ws, 0, clear_bytes, stream);

  size_t lds_bytes = (size_t)(2 * 32) * KP * 2      // h staging
                   + (size_t)(32 * XS) * 4          // x preload
                   + (size_t)(Pz * Hz) * 4;         // w_lin (head)
  hipFuncSetAttribute((const void*)lstm2,
                      hipFuncAttributeMaxDynamicSharedMemorySize, (int)lds_bytes);
  lstm2<<<GB * GS, 256, lds_bytes, stream>>>(x, w_ih0, w_hh0, b_ih0, b_hh0,
                                             w_ih1, w_hh1, b_ih1, b_hh1,
                                             w_lin, b_lin, out, bars, h0g, h1g);
}

// Round 5
// 918.495 us; speedup vs baseline: 1.3049x; 1.3049x over previous
//
#include <hip/hip_runtime.h>

// Problem constants
constexpr int Bz = 512;   // batch
constexpr int Tz = 256;   // seq len
constexpr int Hz = 256;   // hidden
constexpr int Pz = 14;    // predict dim
constexpr int GB = 32;    // batch groups
constexpr int GS = 8;     // hidden slices per group
constexpr int BT = 16;    // batch per group (512/32)
constexpr int HU = 32;    // hidden units per slice (256/8)
constexpr int KP = 264;   // LDS h row stride (shorts)
constexpr int XS = 260;   // x LDS row stride (floats)

typedef short s8v __attribute__((ext_vector_type(8)));
typedef float f4v __attribute__((ext_vector_type(4)));
typedef unsigned long long u64;

__device__ __forceinline__ short f2bf(float f) {
  unsigned u = __float_as_uint(f);
  u = (u + 0x7fffu + ((u >> 16) & 1u)) >> 16;   // RNE
  return (short)u;
}
__device__ __forceinline__ float bf2f(short s) {
  return __uint_as_float(((unsigned)(unsigned short)s) << 16);
}
__device__ __forceinline__ float sigm(float v) { return 1.0f / (1.0f + __expf(-v)); }
__device__ __forceinline__ float tanh_f(float v) { return 1.0f - 2.0f / (__expf(2.0f * v) + 1.0f); }

// R5: permuted global h layout [buf][sl(8)][w(4)][B(512)][q(4)] of u32 pairs
// (lo = unit w*4+q, hi = unit 16+w*4+q). Producer epilogue stores ONE coalesced
// u32/lane per layer (256B/wave contiguous) -- no shuffles, no LDS gather, no
// write amplification. The permutation is baked into the one-time register
// A-fragment build: storage k-position kpos <-> true k:
//   kpos = sl*32 + w*8 + q*2 + j,  k_true = sl*32 + w*4 + q + 16*j.
// Reslice GS=8/GB=32/BT=16/HU=32: barrier fan-in 16->8 blocks, stage volume
// halved, B-frag ds_reads halved (16/lane). Weights stay in registers
// (2 m-tiles/wave, 48 s8v = 192 VGPR, 1 wave/SIMD). tid0-only poll + trailing
// barrier (R3-proven structure).
__global__ void __launch_bounds__(256, 1)
lstm2(const float* __restrict__ x,
      const float* __restrict__ w_ih0, const float* __restrict__ w_hh0,
      const float* __restrict__ b_ih0, const float* __restrict__ b_hh0,
      const float* __restrict__ w_ih1, const float* __restrict__ w_hh1,
      const float* __restrict__ b_ih1, const float* __restrict__ b_hh1,
      const float* __restrict__ w_lin, const float* __restrict__ b_lin,
      float* __restrict__ out,
      unsigned* __restrict__ bars,
      short* __restrict__ h0g, short* __restrict__ h1g)
{
  const int blk  = blockIdx.x;
  const int g    = blk >> 3;      // batch group (32)
  const int sl   = blk & 7;       // hidden slice (8)
  const int tid  = threadIdx.x;
  const int w    = tid >> 6;      // wave
  const int lane = tid & 63;
  const int q    = lane >> 4;
  const int l15  = lane & 15;     // batch within group (n index)
  const int gbase = g * BT;

  extern __shared__ char smem_raw[];
  short* h0s = (short*)smem_raw;          // [BT][KP] staged h0[s-1], kpos order
  short* h1s = h0s + BT * KP;             // [BT][KP] staged h1[s-2]
  float* xls = (float*)(h1s + BT * KP);   // [BT][XS] x preload
  float* wls = xls + BT * XS;             // [Pz][256] w_lin permuted to kpos order

  // ---- one-time: weights -> register A-fragments (permuted k gather) ----
  // wave handles m-tiles mt in {w, 4+w}: rows rr = mt*16+l15, rr = unit*4+gate.
  // acc[r] of tile mti: unit uA = w*4+q (mti=0), uB = 16+w*4+q (mti=1), gate r.
  s8v Wf[3][2][8];   // [mat: hh0, ih1, hh1][mti][kt]
  {
    const float* wsrc[3] = {w_hh0, w_ih1, w_hh1};
    #pragma unroll
    for (int mat = 0; mat < 3; ++mat) {
      #pragma unroll
      for (int mti = 0; mti < 2; ++mti) {
        int rr = (w + mti * 4) * 16 + l15;
        int grow = (rr & 3) * Hz + sl * HU + (rr >> 2);
        const float* p = wsrc[mat] + (size_t)grow * Hz;
        #pragma unroll
        for (int kt = 0; kt < 8; ++kt) {
          s8v f;
          #pragma unroll
          for (int j = 0; j < 8; ++j) {
            int ktrue = kt * 32 + q * 4 + (j >> 1) + 16 * (j & 1);
            f[j] = f2bf(p[ktrue]);
          }
          Wf[mat][mti][kt] = f;
        }
      }
    }
  }
  // per-lane epilogue constants: units uA, uB; gates r=0..3
  const int uA = w * 4 + q, uB = 16 + w * 4 + q;
  float wihA[4], wihB[4], b0A[4], b0B[4], b1A[4], b1B[4];
  #pragma unroll
  for (int r = 0; r < 4; ++r) {
    int ga_ = r * Hz + sl * HU + uA;
    int gb_ = r * Hz + sl * HU + uB;
    wihA[r] = w_ih0[ga_];              wihB[r] = w_ih0[gb_];
    b0A[r]  = b_ih0[ga_] + b_hh0[ga_]; b0B[r]  = b_ih0[gb_] + b_hh0[gb_];
    b1A[r]  = b_ih1[ga_] + b_hh1[ga_]; b1B[r]  = b_ih1[gb_] + b_hh1[gb_];
  }
  float c0A = 0.f, c0B = 0.f, c1A = 0.f, c1B = 0.f;   // cell states in VGPRs

  // ---- preload x (this group's 16 batches) and permuted w_lin (head) ----
  for (int i = tid; i < BT * (Tz / 4); i += 256) {   // 1024 float4
    int b = i >> 6, c4 = i & 63;
    f4v v = *(const f4v*)(x + (size_t)(gbase + b) * Tz + c4 * 4);
    *(f4v*)(xls + b * XS + c4 * 4) = v;
  }
  if (sl == 0) {
    for (int i = tid; i < Pz * Hz; i += 256) {
      int p = i >> 8, kpos = i & 255;
      int sl2 = kpos >> 5, w2 = (kpos >> 3) & 3, q2 = (kpos >> 1) & 3, jj = kpos & 1;
      wls[i] = w_lin[p * Hz + sl2 * 32 + w2 * 4 + q2 + 16 * jj];
    }
  }

  unsigned* bar = bars + (g << 4);   // 64B-separated counter per group

  for (int s = 0; s <= Tz; ++s) {
    // ---- stage h0[s-1] (buf (s+1)&1) and h1[s-2] (buf s&1): 4+4 u64 sc1 loads ----
    {
      const u64* s0 = (const u64*)h0g + (size_t)((s + 1) & 1) * 32768;
      const u64* s1 = (const u64*)h1g + (size_t)(s & 1) * 32768;
      u64 r0[4], r1[4];
      #pragma unroll
      for (int k = 0; k < 4; ++k) {
        int i = tid + k * 256;
        int c = i & 1, b = (i >> 1) & 15, slw = i >> 5;
        size_t gi = ((size_t)slw * Bz + gbase + b) * 2 + c;
        r0[k] = __hip_atomic_load(s0 + gi, __ATOMIC_RELAXED, __HIP_MEMORY_SCOPE_AGENT);
        r1[k] = __hip_atomic_load(s1 + gi, __ATOMIC_RELAXED, __HIP_MEMORY_SCOPE_AGENT);
      }
      #pragma unroll
      for (int k = 0; k < 4; ++k) {
        int i = tid + k * 256;
        int c = i & 1, b = (i >> 1) & 15, slw = i >> 5;
        *(u64*)(h0s + b * KP + slw * 8 + c * 4) = r0[k];
        *(u64*)(h1s + b * KP + slw * 8 + c * 4) = r1[k];
      }
    }
    __syncthreads();

    // ---- fused MFMA: L0 (16) + L1 (32); weights from regs; 16 b128 LDS reads ----
    f4v a0A = {0.f,0.f,0.f,0.f}, a0B = {0.f,0.f,0.f,0.f};
    f4v a1A = {0.f,0.f,0.f,0.f}, a1B = {0.f,0.f,0.f,0.f};
    const short* H0f = h0s + l15 * KP + q * 8;
    const short* H1f = h1s + l15 * KP + q * 8;
    #pragma unroll
    for (int kt = 0; kt < 8; ++kt) {
      s8v h0v = *(const s8v*)(H0f + kt * 32);
      s8v h1v = *(const s8v*)(H1f + kt * 32);
      a0A = __builtin_amdgcn_mfma_f32_16x16x32_bf16(Wf[0][0][kt], h0v, a0A, 0, 0, 0);
      a0B = __builtin_amdgcn_mfma_f32_16x16x32_bf16(Wf[0][1][kt], h0v, a0B, 0, 0, 0);
      a1A = __builtin_amdgcn_mfma_f32_16x16x32_bf16(Wf[1][0][kt], h0v, a1A, 0, 0, 0);
      a1B = __builtin_amdgcn_mfma_f32_16x16x32_bf16(Wf[1][1][kt], h0v, a1B, 0, 0, 0);
      a1A = __builtin_amdgcn_mfma_f32_16x16x32_bf16(Wf[2][0][kt], h1v, a1A, 0, 0, 0);
      a1B = __builtin_amdgcn_mfma_f32_16x16x32_bf16(Wf[2][1][kt], h1v, a1B, 0, 0, 0);
    }

    // ---- in-register epilogues -> one packed u32 per lane per layer ----
    unsigned pk0 = 0, pk1 = 0;
    if (s < Tz) {
      float xv = xls[l15 * XS + s];
      float iA = sigm  (a0A[0] + xv * wihA[0] + b0A[0]);
      float fA = sigm  (a0A[1] + xv * wihA[1] + b0A[1]);
      float gA = tanh_f(a0A[2] + xv * wihA[2] + b0A[2]);
      float oA = sigm  (a0A[3] + xv * wihA[3] + b0A[3]);
      c0A = fA * c0A + iA * gA;
      float iB = sigm  (a0B[0] + xv * wihB[0] + b0B[0]);
      float fB = sigm  (a0B[1] + xv * wihB[1] + b0B[1]);
      float gB = tanh_f(a0B[2] + xv * wihB[2] + b0B[2]);
      float oB = sigm  (a0B[3] + xv * wihB[3] + b0B[3]);
      c0B = fB * c0B + iB * gB;
      pk0 = (unsigned)(unsigned short)f2bf(oA * tanh_f(c0A))
          | ((unsigned)(unsigned short)f2bf(oB * tanh_f(c0B)) << 16);
    }
    if (s >= 1) {
      float iA = sigm  (a1A[0] + b1A[0]);
      float fA = sigm  (a1A[1] + b1A[1]);
      float gA = tanh_f(a1A[2] + b1A[2]);
      float oA = sigm  (a1A[3] + b1A[3]);
      c1A = fA * c1A + iA * gA;
      float iB = sigm  (a1B[0] + b1B[0]);
      float fB = sigm  (a1B[1] + b1B[1]);
      float gB = tanh_f(a1B[2] + b1B[2]);
      float oB = sigm  (a1B[3] + b1B[3]);
      c1B = fB * c1B + iB * gB;
      pk1 = (unsigned)(unsigned short)f2bf(oA * tanh_f(c1A))
          | ((unsigned)(unsigned short)f2bf(oB * tanh_f(c1B)) << 16);
    }

    // ---- coalesced permuted stores: u32 at [buf][sl][w][gbase+l15][q] ----
    {
      size_t base = ((size_t)(sl * 4 + w) * Bz + gbase + l15) * 4 + q;
      if (s < Tz)
        __hip_atomic_store((unsigned*)h0g + (size_t)(s & 1) * 65536 + base,
                           pk0, __ATOMIC_RELAXED, __HIP_MEMORY_SCOPE_AGENT);
      if (s >= 1)
        __hip_atomic_store((unsigned*)h1g + (size_t)((s - 1) & 1) * 65536 + base,
                           pk1, __ATOMIC_RELAXED, __HIP_MEMORY_SCOPE_AGENT);
    }

    // ---- group barrier: syncthreads drains vmcnt(0) per wave (stores at LLC),
    // tid0 bumps + polls, trailing syncthreads releases block ----
    __syncthreads();
    if (tid == 0) {
      __hip_atomic_fetch_add(bar, 1u, __ATOMIC_RELAXED, __HIP_MEMORY_SCOPE_AGENT);
      const unsigned tgt = (unsigned)(GS * (s + 1));
      while (__hip_atomic_load(bar, __ATOMIC_RELAXED, __HIP_MEMORY_SCOPE_AGENT) < tgt)
        __builtin_amdgcn_s_sleep(1);
    }
    __syncthreads();
  }

  // ---- final head (sl==0 blocks): out = h1[T-1] @ w_lin^T + b_lin ----
  if (sl == 0) {
    const u64* s1 = (const u64*)h1g + (size_t)((Tz - 1) & 1) * 32768;
    for (int k = 0; k < 4; ++k) {
      int i = tid + k * 256;
      int c = i & 1, b = (i >> 1) & 15, slw = i >> 5;
      u64 v = __hip_atomic_load(s1 + ((size_t)slw * Bz + gbase + b) * 2 + c,
                                __ATOMIC_RELAXED, __HIP_MEMORY_SCOPE_AGENT);
      *(u64*)(h0s + b * KP + slw * 8 + c * 4) = v;
    }
    __syncthreads();
    for (int i = tid; i < BT * Pz; i += 256) {
      int b = i / Pz, p = i - b * Pz;
      const float* wr = wls + p * Hz;
      float acc = b_lin[p];
      for (int kk = 0; kk < Hz; ++kk)
        acc += bf2f(h0s[b * KP + kk]) * wr[kk];   // both in kpos order
      out[(gbase + b) * Pz + p] = acc;
    }
  }
}

extern "C" void kernel_launch(void* const* d_in, const int* in_sizes, int n_in,
                              void* d_out, int out_size, void* d_ws, size_t ws_size,
                              hipStream_t stream) {
  const float* x     = (const float*)d_in[0];
  const float* w_ih0 = (const float*)d_in[1];
  const float* w_hh0 = (const float*)d_in[2];
  const float* b_ih0 = (const float*)d_in[3];
  const float* b_hh0 = (const float*)d_in[4];
  const float* w_ih1 = (const float*)d_in[5];
  const float* w_hh1 = (const float*)d_in[6];
  const float* b_ih1 = (const float*)d_in[7];
  const float* b_hh1 = (const float*)d_in[8];
  const float* w_lin = (const float*)d_in[9];
  const float* b_lin = (const float*)d_in[10];
  float* out = (float*)d_out;

  unsigned char* ws = (unsigned char*)d_ws;
  unsigned* bars = (unsigned*)ws;                              // 16KB: barrier counters
  short* h0g = (short*)(ws + 16384);                           // [2][256][512] bf16 permuted
  short* h1g = (short*)(ws + 16384 + 2 * Bz * Hz * 2);
  size_t clear_bytes = 16384 + 2 * (size_t)(2 * Bz * Hz * 2);  // counters + h buffers
  hipMemsetAsync(d_ws, 0, clear_bytes, stream);

  size_t lds_bytes = (size_t)(2 * BT) * KP * 2     // h staging
                   + (size_t)(BT * XS) * 4         // x preload
                   + (size_t)(Pz * Hz) * 4;        // permuted w_lin (head)
  hipFuncSetAttribute((const void*)lstm2,
                      hipFuncAttributeMaxDynamicSharedMemorySize, (int)lds_bytes);
  lstm2<<<GB * GS, 256, lds_bytes, stream>>>(x, w_ih0, w_hh0, b_ih0, b_hh0,
                                             w_ih1, w_hh1, b_ih1, b_hh1,
                                             w_lin, b_lin, out, bars, h0g, h1g);
}